// Round 6
// baseline (288.908 us; speedup 1.0000x reference)
//
#include <hip/hip_runtime.h>
#include <stdint.h>

// K-Planes hash-grid encoder, MI355X.
// Unified cost model (r2-r5): ~4.1 us per million vector-memory requests
// system-wide. Structure:
//  - K0 kplane_pack: pts -> pts2[plane][pt] float2 (in d_out scratch).
//    Kills stride-12B coord re-reads (11.8M reqs -> 3.9M).
//  - K1 kplane_hi: levels 8-15 (24 groups = 3 phases x 8 XCDs), XCD-L2
//    residency via b&7 (confirmed r2), even-u0 float4 corner pairing,
//    4 pts/thread MLP, coalesced pts2 reads.
//  - K2 kplane_midlds: ONE kernel, 3 branch regions:
//      mid   (lvl 6-7, row-striped LDS, C=16)
//      ldsA  (lvl 0-4 ALL staged in one 57KB LDS block, C=16)
//      ldsB  (lvl 5, 52.5KB LDS, C=16)
//  - K3 kplane_combine: multiply 3 planes, LDS transpose, coalesced out.
// Plan B fallback (ws < 201.4 MB): r2 3-pass + transpose. Last resort: mono.

#define NPTS   524288u
#define TSIZE  524288u      // 2^19 entries per (plane,level) table
#define TMASK  0x7FFFFu
#define PRIME1 2654435761u

// floor(16 * 1.3819^l) computed in float64 (matches numpy reference exactly)
__constant__ float c_res[16] = {
    16.f, 22.f, 30.f, 42.f, 58.f, 80.f, 111.f, 153.f,
    212.f, 294.f, 406.f, 561.f, 775.f, 1072.f, 1481.f, 2047.f
};

// ldsA: levels 0-4, R = res+1, LDS offsets = prefix of R^2 (total 7109)
__constant__ int c_RA[5]   = {17, 23, 31, 43, 59};
__constant__ int c_offA[5] = {0, 289, 818, 1779, 3628};

// mid stripes: local 0-1 = level 6 (R=112), 2-5 = level 7 (R=154).
__constant__ uint16_t c_mid_lo[6]  = {0, 56, 0, 39, 78, 117};
__constant__ uint16_t c_mid_hiX[6] = {56, 112, 39, 78, 117, 154};

// ---------------- K0: pack per-plane coords ---------------------------------
__global__ __launch_bounds__(256) void kplane_pack(
    const float* __restrict__ pts,
    float2* __restrict__ pts2)        // (3, NPTS) float2, in d_out scratch
{
    const uint32_t pt = blockIdx.x * 256u + threadIdx.x;
    const float x = pts[pt * 3u + 0u];
    const float y = pts[pt * 3u + 1u];
    const float z = pts[pt * 3u + 2u];
    pts2[            pt] = make_float2(x, y);   // plane 0
    pts2[NPTS      + pt] = make_float2(x, z);   // plane 1
    pts2[2u * NPTS + pt] = make_float2(y, z);   // plane 2
}

// ---------------- K1: levels 8-15, L2-resident gather, corner pairing -------
__global__ __launch_bounds__(256) void kplane_hi(
    const float2* __restrict__ pts2,
    const float2* __restrict__ tab,
    float2* __restrict__ ws)
{
    const uint32_t b     = blockIdx.x;
    const uint32_t xcd   = b & 7u;
    const uint32_t s     = b >> 3;
    const uint32_t phase = s >> 9;           // 0..2  (exactly 24 slots)
    const uint32_t chunk = s & 511u;         // 512 chunks x 1024 pts
    const uint32_t plane = phase;
    const uint32_t lvl   = 8u + ((xcd + 3u * phase) & 7u);
    const uint32_t g     = plane * 16u + lvl;
    const float    res   = c_res[lvl];
    const uint32_t base  = g * TSIZE;
    const float4* __restrict__ tab4 = (const float4*)tab;
    const uint32_t b4    = g * (TSIZE / 2u);
    const uint32_t pt0   = chunk * 1024u + threadIdx.x;
    const float2* __restrict__ pp = pts2 + (size_t)plane * NPTS;

    float4 P0[4], P1[4];
    float2 Q0[4], Q1[4];
    float  r0[4], r1[4];
    uint32_t sel0[4], sel1[4], oddm[4];

#pragma unroll
    for (int k = 0; k < 4; ++k) {            // issue all loads first
        const uint32_t pt = pt0 + (uint32_t)k * 256u;
        const float2 c2 = pp[pt];
        const float s0 = c2.x * res;
        const float s1 = c2.y * res;
        const float f0 = floorf(s0);
        const float f1 = floorf(s1);
        r0[k] = s0 - f0;                     // exact f32 match to reference
        r1[k] = s1 - f1;
        const uint32_t u0  = (uint32_t)f0;
        const uint32_t hy0 = (uint32_t)f1 * PRIME1;
        const uint32_t hy1 = hy0 + PRIME1;
        const uint32_t i00 = ( u0        ^ hy0) & TMASK;
        const uint32_t i01 = ( u0        ^ hy1) & TMASK;
        const uint32_t i10 = ((u0 + 1u)  ^ hy0) & TMASK;
        const uint32_t i11 = ((u0 + 1u)  ^ hy1) & TMASK;
        sel0[k] = i00 & 1u;
        sel1[k] = i01 & 1u;
        oddm[k] = u0 & 1u;
        P0[k] = tab4[b4 + (i00 >> 1)];       // covers t00 (+t10 if u0 even)
        P1[k] = tab4[b4 + (i01 >> 1)];       // covers t01 (+t11 if u0 even)
        Q0[k] = make_float2(0.f, 0.f);
        Q1[k] = make_float2(0.f, 0.f);
        if (oddm[k]) {                       // exec-masked, ~50% lanes
            Q0[k] = tab[base + i10];
            Q1[k] = tab[base + i11];
        }
    }
#pragma unroll
    for (int k = 0; k < 4; ++k) {
        const uint32_t pt = pt0 + (uint32_t)k * 256u;
        const float2 lo0 = make_float2(P0[k].x, P0[k].y);
        const float2 hi0 = make_float2(P0[k].z, P0[k].w);
        const float2 lo1 = make_float2(P1[k].x, P1[k].y);
        const float2 hi1 = make_float2(P1[k].z, P1[k].w);
        const float2 t00 = sel0[k] ? hi0 : lo0;
        const float2 t01 = sel1[k] ? hi1 : lo1;
        const float2 t10 = oddm[k] ? Q0[k] : (sel0[k] ? lo0 : hi0);
        const float2 t11 = oddm[k] ? Q1[k] : (sel1[k] ? lo1 : hi1);
        const float w00 = (1.f - r0[k]) * (1.f - r1[k]);
        const float w01 = (1.f - r0[k]) * r1[k];
        const float w10 = r0[k] * (1.f - r1[k]);
        const float w11 = r0[k] * r1[k];
        ws[g * NPTS + pt] = make_float2(
            w00 * t00.x + w01 * t01.x + w10 * t10.x + w11 * t11.x,
            w00 * t00.y + w01 * t01.y + w10 * t10.y + w11 * t11.y);
    }
}

// ---------------- K2: levels 0-7 via LDS, one kernel, 3 regions -------------
// grid: [0,288) mid stripes (18 sg x C=16); [288,336) ldsA; [336,384) ldsB
__global__ __launch_bounds__(512) void kplane_midlds(
    const float2* __restrict__ pts2,
    const float2* __restrict__ tab,
    float2* __restrict__ ws)
{
    __shared__ float2 sm[7109];              // 56.9 KB, union of all regions
    const uint32_t b = blockIdx.x;
    const uint32_t t = threadIdx.x;

    if (b < 288u) {
        // ---- mid: levels 6-7, row-striped ----
        const uint32_t sg    = b >> 4;       // 0..17
        const uint32_t chunk = b & 15u;      // C=16, 32768 pts each
        const uint32_t plane = sg / 6u;
        const uint32_t local = sg - plane * 6u;
        const uint32_t lvl   = (local < 2u) ? 6u : 7u;
        const uint32_t g     = plane * 16u + lvl;
        const uint32_t R     = (lvl == 6u) ? 112u : 154u;
        const uint32_t lo    = c_mid_lo[local];
        const uint32_t hiX   = c_mid_hiX[local];
        const uint32_t nrows = ((hiX < R ? hiX : R - 1u) - lo) + 1u;
        const uint32_t E     = nrows * R;
        const float    res   = c_res[lvl];
        const uint32_t base  = g * TSIZE;

        for (uint32_t i = t; i < E; i += 512u) {
            const uint32_t rr = i / R;
            const uint32_t cy = i - rr * R;
            const uint32_t cx = lo + rr;
            sm[i] = tab[base + ((cx ^ (cy * PRIME1)) & TMASK)];
        }
        __syncthreads();

        const float2* __restrict__ pp = pts2 + (size_t)plane * NPTS;
        const uint32_t pt0 = chunk * 32768u + t;

#pragma unroll 4
        for (uint32_t k = 0; k < 64u; ++k) {
            const uint32_t pt = pt0 + k * 512u;
            const float2 c2 = pp[pt];
            const float s0 = c2.x * res;
            const float s1 = c2.y * res;
            const float f0 = floorf(s0);
            const float f1 = floorf(s1);
            const uint32_t u0 = (uint32_t)f0;
            if (u0 >= lo && u0 < hiX) {
                const float r0 = s0 - f0;
                const float r1 = s1 - f1;
                const uint32_t ci = (u0 - lo) * R + (uint32_t)f1;
                const float2 q00 = sm[ci];
                const float2 q01 = sm[ci + 1u];
                const float2 q10 = sm[ci + R];
                const float2 q11 = sm[ci + R + 1u];
                const float w00 = (1.f - r0) * (1.f - r1);
                const float w01 = (1.f - r0) * r1;
                const float w10 = r0 * (1.f - r1);
                const float w11 = r0 * r1;
                ws[g * NPTS + pt] = make_float2(
                    w00 * q00.x + w01 * q01.x + w10 * q10.x + w11 * q11.x,
                    w00 * q00.y + w01 * q01.y + w10 * q10.y + w11 * q11.y);
            }
        }
    } else if (b < 336u) {
        // ---- ldsA: levels 0-4, all staged at once ----
        const uint32_t idx   = b - 288u;
        const uint32_t plane = idx >> 4;     // 0..2
        const uint32_t chunk = idx & 15u;    // C=16

#pragma unroll
        for (int l = 0; l < 5; ++l) {
            const uint32_t R    = (uint32_t)c_RA[l];
            const uint32_t E    = R * R;
            const uint32_t off  = (uint32_t)c_offA[l];
            const uint32_t base = (plane * 16u + (uint32_t)l) * TSIZE;
            for (uint32_t i = t; i < E; i += 512u) {
                const uint32_t cx = i / R;
                const uint32_t cy = i - cx * R;
                sm[off + i] = tab[base + ((cx ^ (cy * PRIME1)) & TMASK)];
            }
        }
        __syncthreads();

        const float2* __restrict__ pp = pts2 + (size_t)plane * NPTS;
        const uint32_t pt0 = chunk * 32768u + t;

#pragma unroll 2
        for (uint32_t k = 0; k < 64u; ++k) {
            const uint32_t pt = pt0 + k * 512u;
            const float2 c2 = pp[pt];
#pragma unroll
            for (int l = 0; l < 5; ++l) {
                const uint32_t R   = (uint32_t)c_RA[l];
                const uint32_t off = (uint32_t)c_offA[l];
                const float res = c_res[l];
                const float s0 = c2.x * res;
                const float s1 = c2.y * res;
                const float f0 = floorf(s0);
                const float f1 = floorf(s1);
                const float r0 = s0 - f0;
                const float r1 = s1 - f1;
                const uint32_t ci = off + (uint32_t)f0 * R + (uint32_t)f1;
                const float2 q00 = sm[ci];
                const float2 q01 = sm[ci + 1u];
                const float2 q10 = sm[ci + R];
                const float2 q11 = sm[ci + R + 1u];
                const float w00 = (1.f - r0) * (1.f - r1);
                const float w01 = (1.f - r0) * r1;
                const float w10 = r0 * (1.f - r1);
                const float w11 = r0 * r1;
                ws[(plane * 16u + (uint32_t)l) * NPTS + pt] = make_float2(
                    w00 * q00.x + w01 * q01.x + w10 * q10.x + w11 * q11.x,
                    w00 * q00.y + w01 * q01.y + w10 * q10.y + w11 * q11.y);
            }
        }
    } else {
        // ---- ldsB: level 5 (R=81, E=6561) ----
        const uint32_t idx   = b - 336u;
        const uint32_t plane = idx >> 4;
        const uint32_t chunk = idx & 15u;
        const uint32_t R     = 81u;
        const uint32_t E     = 6561u;
        const float    res   = 80.f;
        const uint32_t g     = plane * 16u + 5u;
        const uint32_t base  = g * TSIZE;

        for (uint32_t i = t; i < E; i += 512u) {
            const uint32_t cx = i / R;
            const uint32_t cy = i - cx * R;
            sm[i] = tab[base + ((cx ^ (cy * PRIME1)) & TMASK)];
        }
        __syncthreads();

        const float2* __restrict__ pp = pts2 + (size_t)plane * NPTS;
        const uint32_t pt0 = chunk * 32768u + t;

#pragma unroll 4
        for (uint32_t k = 0; k < 64u; ++k) {
            const uint32_t pt = pt0 + k * 512u;
            const float2 c2 = pp[pt];
            const float s0 = c2.x * res;
            const float s1 = c2.y * res;
            const float f0 = floorf(s0);
            const float f1 = floorf(s1);
            const float r0 = s0 - f0;
            const float r1 = s1 - f1;
            const uint32_t ci = (uint32_t)f0 * R + (uint32_t)f1;
            const float2 q00 = sm[ci];
            const float2 q01 = sm[ci + 1u];
            const float2 q10 = sm[ci + R];
            const float2 q11 = sm[ci + R + 1u];
            const float w00 = (1.f - r0) * (1.f - r1);
            const float w01 = (1.f - r0) * r1;
            const float w10 = r0 * (1.f - r1);
            const float w11 = r0 * r1;
            ws[g * NPTS + pt] = make_float2(
                w00 * q00.x + w01 * q01.x + w10 * q10.x + w11 * q11.x,
                w00 * q00.y + w01 * q01.y + w10 * q10.y + w11 * q11.y);
        }
    }
}

// ---------------- K3: combine 3 planes, transpose via LDS -------------------
__global__ __launch_bounds__(256) void kplane_combine(
    const float2* __restrict__ ws,    // (48, NPTS)
    float2* __restrict__ out)         // (NPTS, 16)
{
    __shared__ float2 tile[16][65];
    const uint32_t pt0 = blockIdx.x * 64u;
    const uint32_t t   = threadIdx.x;
    const uint32_t lr  = t >> 6;
    const uint32_t ptl = t & 63u;

#pragma unroll
    for (int k = 0; k < 4; ++k) {
        const uint32_t lvl = (uint32_t)k * 4u + lr;
        const float2 a = ws[( 0u + lvl) * NPTS + pt0 + ptl];
        const float2 b = ws[(16u + lvl) * NPTS + pt0 + ptl];
        const float2 c = ws[(32u + lvl) * NPTS + pt0 + ptl];
        tile[lvl][ptl] = make_float2(a.x * b.x * c.x, a.y * b.y * c.y);
    }
    __syncthreads();
#pragma unroll
    for (int k = 0; k < 4; ++k) {
        const uint32_t e      = t + (uint32_t)k * 256u;
        const uint32_t out_lv = e & 15u;
        const uint32_t out_pt = e >> 4;
        out[(pt0 + out_pt) * 16u + out_lv] = tile[out_lv][out_pt];
    }
}

// ---------------- Plan B fallback: r2 3-pass + transpose --------------------
template <int P, bool FIRST>
__global__ __launch_bounds__(256) void kplane_pass(
    const float* __restrict__ pts,
    const float2* __restrict__ tab,
    float2* __restrict__ ws)          // (16, NPTS)
{
    const uint32_t b     = blockIdx.x;
    const uint32_t xcd   = b & 7u;
    const uint32_t s     = b >> 3;
    const uint32_t gi    = s >> 11;
    const uint32_t chunk = s & 2047u;
    const uint32_t lvl   = gi * 8u + xcd;
    const uint32_t pt    = chunk * 256u + threadIdx.x;

    constexpr int c0 = (P == 2) ? 1 : 0;
    constexpr int c1 = (P == 0) ? 1 : 2;

    const float a0  = pts[pt * 3u + c0];
    const float a1  = pts[pt * 3u + c1];
    const float res = c_res[lvl];

    const float s0 = a0 * res;
    const float s1 = a1 * res;
    const float f0 = floorf(s0);
    const float f1 = floorf(s1);
    const float r0 = s0 - f0;
    const float r1 = s1 - f1;
    const uint32_t u0 = (uint32_t)f0;
    const uint32_t hy0  = (uint32_t)f1 * PRIME1;
    const uint32_t hy1  = hy0 + PRIME1;
    const uint32_t base = ((uint32_t)P * 16u + lvl) * TSIZE;

    const float2 t00 = tab[base + (( u0       ^ hy0) & TMASK)];
    const float2 t01 = tab[base + (( u0       ^ hy1) & TMASK)];
    const float2 t10 = tab[base + (((u0 + 1u) ^ hy0) & TMASK)];
    const float2 t11 = tab[base + (((u0 + 1u) ^ hy1) & TMASK)];

    const float w00 = (1.f - r0) * (1.f - r1);
    const float w01 = (1.f - r0) * r1;
    const float w10 = r0 * (1.f - r1);
    const float w11 = r0 * r1;

    const float e0 = w00 * t00.x + w01 * t01.x + w10 * t10.x + w11 * t11.x;
    const float e1 = w00 * t00.y + w01 * t01.y + w10 * t10.y + w11 * t11.y;

    const uint32_t widx = lvl * NPTS + pt;
    if (FIRST) {
        ws[widx] = make_float2(e0, e1);
    } else {
        const float2 prev = ws[widx];
        ws[widx] = make_float2(prev.x * e0, prev.y * e1);
    }
}

__global__ __launch_bounds__(256) void kplane_transpose(
    const float2* __restrict__ ws, float2* __restrict__ out)
{
    const uint32_t tid = blockIdx.x * 256u + threadIdx.x;
    const uint32_t lvl = tid & 15u;
    const uint32_t pt  = tid >> 4;
    out[tid] = ws[lvl * NPTS + pt];
}

__global__ __launch_bounds__(256) void kplane_mono(
    const float* __restrict__ pts,
    const float2* __restrict__ tab,
    float2* __restrict__ out)
{
    const uint32_t tid = blockIdx.x * 256u + threadIdx.x;
    const uint32_t pt  = tid >> 4;
    const uint32_t lvl = tid & 15u;
    const float x = pts[pt * 3u + 0u];
    const float y = pts[pt * 3u + 1u];
    const float z = pts[pt * 3u + 2u];
    const float res = c_res[lvl];
    const float a0[3] = {x, x, y};
    const float a1[3] = {y, z, z};
    float p0 = 1.f, p1 = 1.f;
#pragma unroll
    for (int pl = 0; pl < 3; ++pl) {
        const float s0 = a0[pl] * res;
        const float s1 = a1[pl] * res;
        const float f0 = floorf(s0);
        const float f1 = floorf(s1);
        const float r0 = s0 - f0;
        const float r1 = s1 - f1;
        const uint32_t u0 = (uint32_t)f0;
        const uint32_t hy0 = (uint32_t)f1 * PRIME1;
        const uint32_t hy1 = hy0 + PRIME1;
        const uint32_t base = ((uint32_t)pl * 16u + lvl) * TSIZE;
        const float2 t00 = tab[base + (( u0       ^ hy0) & TMASK)];
        const float2 t01 = tab[base + (( u0       ^ hy1) & TMASK)];
        const float2 t10 = tab[base + (((u0 + 1u) ^ hy0) & TMASK)];
        const float2 t11 = tab[base + (((u0 + 1u) ^ hy1) & TMASK)];
        const float w00 = (1.f - r0) * (1.f - r1);
        const float w01 = (1.f - r0) * r1;
        const float w10 = r0 * (1.f - r1);
        const float w11 = r0 * r1;
        p0 *= w00 * t00.x + w01 * t01.x + w10 * t10.x + w11 * t11.x;
        p1 *= w00 * t00.y + w01 * t01.y + w10 * t10.y + w11 * t11.y;
    }
    out[pt * 16u + lvl] = make_float2(p0, p1);
}

extern "C" void kernel_launch(void* const* d_in, const int* in_sizes, int n_in,
                              void* d_out, int out_size, void* d_ws, size_t ws_size,
                              hipStream_t stream) {
    const float*  pts = (const float*)d_in[0];
    const float2* tab = (const float2*)d_in[1];
    float2*       out = (float2*)d_out;

    const size_t wsA = (size_t)48 * NPTS * sizeof(float2);   // 201.3 MB
    const size_t wsB = (size_t)16 * NPTS * sizeof(float2);   //  67.1 MB
    dim3 block256(256u), block512(512u);

    if (ws_size >= wsA) {
        float2* ws   = (float2*)d_ws;
        float2* pts2 = (float2*)d_out;       // 12.6 MB scratch in d_out,
                                             // dead before combine writes
        hipLaunchKernelGGL(kplane_pack, dim3(NPTS / 256u), block256, 0, stream,
                           pts, pts2);
        dim3 hgrid(3u * 8u * 512u);                          // 12288 blocks
        hipLaunchKernelGGL(kplane_hi, hgrid, block256, 0, stream, pts2, tab, ws);
        dim3 mgrid(384u);
        hipLaunchKernelGGL(kplane_midlds, mgrid, block512, 0, stream, pts2, tab, ws);
        dim3 cgrid(NPTS / 64u);                              // 8192 blocks
        hipLaunchKernelGGL(kplane_combine, cgrid, block256, 0, stream, ws, out);
    } else if (ws_size >= wsB) {
        float2* ws = (float2*)d_ws;
        dim3 grid(16u * (NPTS / 256u));
        hipLaunchKernelGGL((kplane_pass<0, true >), grid, block256, 0, stream, pts, tab, ws);
        hipLaunchKernelGGL((kplane_pass<1, false>), grid, block256, 0, stream, pts, tab, ws);
        hipLaunchKernelGGL((kplane_pass<2, false>), grid, block256, 0, stream, pts, tab, ws);
        dim3 tgrid((NPTS * 16u) / 256u);
        hipLaunchKernelGGL(kplane_transpose, tgrid, block256, 0, stream, ws, out);
    } else {
        dim3 grid((NPTS * 16u) / 256u);
        hipLaunchKernelGGL(kplane_mono, grid, block256, 0, stream, pts, tab, out);
    }
}